// Round 5
// baseline (239.014 us; speedup 1.0000x reference)
//
#include <hip/hip_runtime.h>
#include <hip/hip_bf16.h>
#include <stdint.h>
#include <math.h>

typedef unsigned short ushort_t;
typedef __attribute__((ext_vector_type(4))) float f32x4;
typedef __attribute__((ext_vector_type(8))) __bf16 bf16x8;
typedef __attribute__((ext_vector_type(8))) unsigned short ushort8;
typedef __attribute__((ext_vector_type(4))) unsigned short ushort4v;

__device__ __forceinline__ float bf2f(ushort_t u) {
  union { unsigned u32; float f; } x; x.u32 = ((unsigned)u) << 16; return x.f;
}
__device__ __forceinline__ ushort_t f2bf(float f) {
  union { float f; unsigned u; } x; x.f = f;
  unsigned r = x.u + 0x7FFF + ((x.u >> 16) & 1);
  return (ushort_t)(r >> 16);
}

// async global->LDS, 16 bytes per lane (global_load_lds_dwordx4)
__device__ __forceinline__ void gld16(const ushort_t* g, ushort_t* l) {
  __builtin_amdgcn_global_load_lds(
      (const __attribute__((address_space(1))) uint32_t*)g,
      (__attribute__((address_space(3))) uint32_t*)l, 16, 0, 0);
}

// ------- merged cast fp32->bf16 (x,Wq,Wk,Wv) + rowsum zero (4 blocks) ------
__global__ __launch_bounds__(256) void cast_all_kernel(
    const float* __restrict__ x, const float* __restrict__ wq,
    const float* __restrict__ wk, const float* __restrict__ wv,
    ushort_t* __restrict__ xb, ushort_t* __restrict__ wqb,
    ushort_t* __restrict__ wkb, ushort_t* __restrict__ wvb,
    float* __restrict__ rowsum) {
  int blk = blockIdx.x;
  if (blk >= 4096 + 1536) {  // rowsum zero: 4 blocks x 256 thr x 8 floats
    int idx = (blk - (4096 + 1536)) * 256 + threadIdx.x;  // 0..1023
    f32x4 z = {0.f, 0.f, 0.f, 0.f};
    ((f32x4*)rowsum)[idx * 2] = z;
    ((f32x4*)rowsum)[idx * 2 + 1] = z;
    return;
  }
  const float* in;
  ushort_t* out;
  int i;
  if (blk < 4096) {               // x: 8388608 elems = 4096 blocks
    in = x; out = xb; i = blk * 256 + threadIdx.x;
  } else {
    int w = (blk - 4096) >> 9;    // 512 blocks per weight matrix
    int lb = (blk - 4096) & 511;
    in = (w == 0) ? wq : (w == 1) ? wk : wv;
    out = (w == 0) ? wqb : (w == 1) ? wkb : wvb;
    i = lb * 256 + threadIdx.x;
  }
  const f32x4* p = (const f32x4*)in;
  f32x4 a = p[2 * i];
  f32x4 b = p[2 * i + 1];
  ushort8 o;
  o[0] = f2bf(a[0]); o[1] = f2bf(a[1]); o[2] = f2bf(a[2]); o[3] = f2bf(a[3]);
  o[4] = f2bf(b[0]); o[5] = f2bf(b[1]); o[6] = f2bf(b[2]); o[7] = f2bf(b[3]);
  *((ushort8*)out + i) = o;
}

// ---------------- PROVEN 128x128 core (256 thr, 3 blocks/CU) --------------
// R3 configuration exactly (R4's launch_bounds(256,4) squeeze REGRESSED:
// MfmaUtil 37->29.7, occupancy unchanged -> reverted to (256,3)).
#define BM 128
#define BN 128
#define BK 64

__device__ __forceinline__ void gemm_core(
    const ushort_t* __restrict__ A, const ushort_t* __restrict__ B, int Kd,
    int kEnd, int m0, int n0, ushort_t* As, ushort_t* Bs, f32x4 (&acc)[4][4]) {
  int tid = threadIdx.x;
  int lane = tid & 63;
  int wave = tid >> 6;
  int wr = (wave >> 1) * 64;
  int wc = (wave & 1) * 64;
  int ln15 = lane & 15;
  int kq = lane >> 4;

  int row = tid >> 3;                              // 0..31 (base row of chunk)
  int ksw = ((tid & 7) ^ (row & 7)) * 8;           // swizzled k-offset (elems)
  const ushort_t* aB = A + (size_t)(m0 + row) * Kd + ksw;
  const ushort_t* bB = B + (size_t)(n0 + row) * Kd + ksw;
  int xk = ln15 & 7;                               // reader un-swizzle key

  for (int k0 = 0; k0 < kEnd; k0 += BK) {
    __syncthreads();
#pragma unroll
    for (int r = 0; r < 4; ++r) {
      gld16(aB + (size_t)(32 * r) * Kd + k0, &As[(tid + 256 * r) * 8]);
      gld16(bB + (size_t)(32 * r) * Kd + k0, &Bs[(tid + 256 * r) * 8]);
    }
    __syncthreads();
#pragma unroll
    for (int s = 0; s < 2; ++s) {
      bf16x8 af[4], bfr[4];
#pragma unroll
      for (int i = 0; i < 4; ++i)
        af[i] = *(const bf16x8*)
            &As[(wr + i * 16 + ln15) * BK + (((s * 4 + kq) ^ xk) * 8)];
#pragma unroll
      for (int j = 0; j < 4; ++j)
        bfr[j] = *(const bf16x8*)
            &Bs[(wc + j * 16 + ln15) * BK + (((s * 4 + kq) ^ xk) * 8)];
#pragma unroll
      for (int i = 0; i < 4; ++i)
#pragma unroll
        for (int j = 0; j < 4; ++j)
          acc[i][j] = __builtin_amdgcn_mfma_f32_16x16x32_bf16(
              af[i], bfr[j], acc[i][j], 0, 0, 0);
    }
  }
}

// S-GEMM: softmax numerator fused; compact triangular causal launch.
__global__ __launch_bounds__(256, 3) void gemm_s(
    const ushort_t* __restrict__ Qg, const ushort_t* __restrict__ Kg,
    ushort_t* __restrict__ Eg, float scale, float* __restrict__ rowsum) {
  int t = blockIdx.x;  // 0..135 triangular index
  int m = (int)((sqrtf(8.f * (float)t + 1.f) - 1.f) * 0.5f);
  while ((m + 1) * (m + 2) / 2 <= t) ++m;
  while (m * (m + 1) / 2 > t) --m;
  int n = t - m * (m + 1) / 2;              // 0..m
  int m0 = m * BM, n0 = n * BN;
  int bz = blockIdx.z;
  const ushort_t* A = Qg + (size_t)bz * (2048 * 1024);
  const ushort_t* B = Kg + (size_t)bz * (2048 * 1024);

  __shared__ ushort_t As[BM * BK];
  __shared__ ushort_t Bs[BN * BK];

  f32x4 acc[4][4];
#pragma unroll
  for (int i = 0; i < 4; ++i)
#pragma unroll
    for (int j = 0; j < 4; ++j) acc[i][j] = f32x4{0.f, 0.f, 0.f, 0.f};

  gemm_core(A, B, 1024, 1024, m0, n0, As, Bs, acc);

  int tid = threadIdx.x;
  int lane = tid & 63;
  int wave = tid >> 6;
  int wr = (wave >> 1) * 64;
  int wc = (wave & 1) * 64;
  int ln15 = lane & 15;
  int kq = lane >> 4;

  ushort_t* C = Eg + (size_t)bz * (2048 * 2048);
  float* rs = rowsum + (size_t)bz * 2048;
#pragma unroll
  for (int i = 0; i < 4; ++i) {
    int row0 = m0 + wr + i * 16 + kq * 4;
#pragma unroll
    for (int r = 0; r < 4; ++r) {
      int grow = row0 + r;
      float psum = 0.f;
#pragma unroll
      for (int j = 0; j < 4; ++j) {
        int col = n0 + wc + j * 16 + ln15;
        float e = (col <= grow) ? __expf(acc[i][j][r] * scale) : 0.f;
        C[(size_t)grow * 2048 + col] = f2bf(e);
        psum += e;
      }
      psum += __shfl_xor(psum, 1);
      psum += __shfl_xor(psum, 2);
      psum += __shfl_xor(psum, 4);
      psum += __shfl_xor(psum, 8);
      if (ln15 == 0) atomicAdd(&rs[grow], psum);
    }
  }
}

// O-GEMM: complementary-K pairing + longest-K first (z<2 -> m reversed).
__global__ __launch_bounds__(256, 3) void gemm_o(
    const ushort_t* __restrict__ Eg, const ushort_t* __restrict__ Vg,
    float* __restrict__ Og, const float* __restrict__ rowsum) {
  int m = (blockIdx.z < 2) ? (int)(gridDim.x - 1 - blockIdx.x)
                           : (int)blockIdx.x;
  int m0 = m * BM, n0 = blockIdx.y * BN;
  int kEnd = min(2048, m0 + BM);
  int bz = blockIdx.z;
  const ushort_t* A = Eg + (size_t)bz * (2048 * 2048);
  const ushort_t* B = Vg + (size_t)bz * (1024 * 2048);

  __shared__ ushort_t As[BM * BK];
  __shared__ ushort_t Bs[BN * BK];

  f32x4 acc[4][4];
#pragma unroll
  for (int i = 0; i < 4; ++i)
#pragma unroll
    for (int j = 0; j < 4; ++j) acc[i][j] = f32x4{0.f, 0.f, 0.f, 0.f};

  gemm_core(A, B, 2048, kEnd, m0, n0, As, Bs, acc);

  int tid = threadIdx.x;
  int lane = tid & 63;
  int wave = tid >> 6;
  int wr = (wave >> 1) * 64;
  int wc = (wave & 1) * 64;
  int ln15 = lane & 15;
  int kq = lane >> 4;

  float* C = Og + (size_t)bz * (2048 * 1024);
  const float* rs = rowsum + (size_t)bz * 2048;
#pragma unroll
  for (int i = 0; i < 4; ++i) {
    int row0 = m0 + wr + i * 16 + kq * 4;
#pragma unroll
    for (int r = 0; r < 4; ++r) {
      float inv = 1.0f / rs[row0 + r];
#pragma unroll
      for (int j = 0; j < 4; ++j) {
        int col = n0 + wc + j * 16 + ln15;
        C[(size_t)(row0 + r) * 1024 + col] = acc[i][j][r] * inv;
      }
    }
  }
}

// ============ 256x256 8-phase QKV (T2+T3+T4+T5 template geometry) =========
// 512 thr = 8 waves (2M x 4N), per-wave C = 128x64 (acc[8][4]). BK=64,
// double-buffered LDS 128 KB. Per 2 K-tiles: 8 phases; phase (buf,mh,ks) =
// {8 ds_read_b128 (4 A-frags of m-half mh + 4 B-frags, k-half ks) || 2-4
// gld16 stages -> lgkmcnt(0) -> setprio(1) + 16 MFMA -> [boundary vmcnt(2)]
// -> s_barrier}. Stage schedule (derived, region-safe: every target's last
// reader finished >=1 barrier earlier):
//   ph1: A(t1)Q1,Q3 + B(t1)r0,r1   (buf1 freed end of prev ph8)
//   ph2: B(t1)r2,r3
//   ph3: A(t0+2)Q0,Q2              (buf0 A mh0 quarters freed end ph2)
//   ph4: --            + vmcnt(2 | 0 at last iter)  [covers t1 reads]
//   ph5: A(t0+2)Q1,Q3              (freed end ph4)
//   ph6: B(t0+2)r0,r1              (buf0 B freed end ph4)
//   ph7: B(t0+2)r2,r3
//   ph8: A(t1+2)Q0,Q2  + vmcnt(2)  [covers next-iter ph1 reads]
// Waits sit BEFORE the barrier so all waves' own loads are landed when any
// wave crosses -> no cross-wave gld16 race. Counted vmcnt never drains the
// pipe mid-loop (T4). Same proven global-source XOR swizzle (0 conflicts).
#define STA(BUF, T, Q) \
  gld16(aS + (size_t)((Q) * 64) * 1024 + (T) * 64, &As[BUF][(Q)*4096 + tid * 8])
#define STB(BUF, T, R) \
  gld16(bS + (size_t)((R) * 64) * 1024 + (T) * 64, &Bs[BUF][(R)*4096 + tid * 8])

#define PHASE(BUF, MH, KS, STAGES, TAIL) do {                               \
    bf16x8 af[4], bfv[4];                                                   \
    _Pragma("unroll")                                                       \
    for (int f = 0; f < 4; ++f)                                             \
      af[f] = *(const bf16x8*)&As[BUF][                                     \
          (wm * 128 + (MH) * 64 + f * 16 + ln15) * 64 +                     \
          ((((KS) * 4 + kq) ^ xk) * 8)];                                    \
    _Pragma("unroll")                                                       \
    for (int n = 0; n < 4; ++n)                                             \
      bfv[n] = *(const bf16x8*)&Bs[BUF][                                    \
          (wn * 64 + n * 16 + ln15) * 64 + ((((KS) * 4 + kq) ^ xk) * 8)];   \
    STAGES;                                                                 \
    asm volatile("s_waitcnt lgkmcnt(0)" ::: "memory");                      \
    __builtin_amdgcn_sched_barrier(0);                                      \
    __builtin_amdgcn_s_setprio(1);                                          \
    _Pragma("unroll")                                                       \
    for (int f = 0; f < 4; ++f)                                             \
      _Pragma("unroll")                                                     \
      for (int n = 0; n < 4; ++n)                                           \
        acc[(MH) * 4 + f][n] = __builtin_amdgcn_mfma_f32_16x16x32_bf16(     \
            af[f], bfv[n], acc[(MH) * 4 + f][n], 0, 0, 0);                  \
    __builtin_amdgcn_s_setprio(0);                                          \
    TAIL;                                                                   \
    __builtin_amdgcn_sched_barrier(0);                                      \
    __builtin_amdgcn_s_barrier();                                           \
    __builtin_amdgcn_sched_barrier(0);                                      \
  } while (0)

__global__ __launch_bounds__(512, 2) void gemm_qkv8p(
    const ushort_t* __restrict__ xb, const ushort_t* __restrict__ wq,
    const ushort_t* __restrict__ wk, const ushort_t* __restrict__ wv,
    ushort_t* __restrict__ Qb, ushort_t* __restrict__ Kb,
    ushort_t* __restrict__ Vt) {
  int m0 = blockIdx.x * 256, n0 = blockIdx.y * 256;
  int z = blockIdx.z;
  const ushort_t* Bw = (z == 0) ? wq : (z == 1) ? wk : wv;
  const int nt = 16;  // 1024 / 64 K-tiles

  __shared__ ushort_t As[2][256 * 64];  // 64 KB
  __shared__ ushort_t Bs[2][256 * 64];  // 64 KB

  int tid = threadIdx.x;
  int lane = tid & 63;
  int wave = tid >> 6;
  int wm = wave >> 2, wn = wave & 3;
  int ln15 = lane & 15, kq = lane >> 4, xk = ln15 & 7;

  // staging source base (proven XOR k-chunk swizzle on the global offset)
  const ushort_t* aS = xb + (size_t)(m0 + (tid >> 3)) * 1024 +
                       (((tid & 7) ^ ((tid >> 3) & 7)) * 8);
  const ushort_t* bS = Bw + (size_t)(n0 + (tid >> 3)) * 1024 +
                       (((tid & 7) ^ ((tid >> 3) & 7)) * 8);

  f32x4 acc[8][4];
#pragma unroll
  for (int a = 0; a < 8; ++a)
#pragma unroll
    for (int n = 0; n < 4; ++n) acc[a][n] = f32x4{0.f, 0.f, 0.f, 0.f};

  // prologue: tile0 full (8 rounds) + A(1) Q0,Q2
  STA(0, 0, 0); STA(0, 0, 1); STA(0, 0, 2); STA(0, 0, 3);
  STB(0, 0, 0); STB(0, 0, 1); STB(0, 0, 2); STB(0, 0, 3);
  STA(1, 1, 0); STA(1, 1, 2);
  asm volatile("s_waitcnt vmcnt(2)" ::: "memory");
  __builtin_amdgcn_sched_barrier(0);
  __builtin_amdgcn_s_barrier();
  __builtin_amdgcn_sched_barrier(0);

  for (int i = 0; i < nt / 2; ++i) {
    int t0 = 2 * i, t1 = 2 * i + 1;
    bool s2 = (t0 + 2) < nt, s3 = (t1 + 2) < nt;
    PHASE(0, 0, 0,
          { STA(1, t1, 1); STA(1, t1, 3); STB(1, t1, 0); STB(1, t1, 1); }, );
    PHASE(0, 0, 1, { STB(1, t1, 2); STB(1, t1, 3); }, );
    PHASE(0, 1, 0, { if (s2) { STA(0, t0 + 2, 0); STA(0, t0 + 2, 2); } }, );
    PHASE(0, 1, 1, , {
      if (s2) { asm volatile("s_waitcnt vmcnt(2)" ::: "memory"); }
      else    { asm volatile("s_waitcnt vmcnt(0)" ::: "memory"); } });
    PHASE(1, 0, 0, { if (s2) { STA(0, t0 + 2, 1); STA(0, t0 + 2, 3); } }, );
    PHASE(1, 0, 1, { if (s2) { STB(0, t0 + 2, 0); STB(0, t0 + 2, 1); } }, );
    PHASE(1, 1, 0, { if (s2) { STB(0, t0 + 2, 2); STB(0, t0 + 2, 3); } }, );
    PHASE(1, 1, 1, { if (s3) { STA(1, t1 + 2, 0); STA(1, t1 + 2, 2); } },
          { asm volatile("s_waitcnt vmcnt(2)" ::: "memory"); });
  }

  // epilogue: C/D layout col = lane&15, row = (lane>>4)*4 + reg (m89)
  if (z < 2) {
    ushort_t* C = (z == 0) ? Qb : Kb;
#pragma unroll
    for (int a = 0; a < 8; ++a) {
      int row0 = m0 + wm * 128 + (a >> 2) * 64 + (a & 3) * 16 + kq * 4;
#pragma unroll
      for (int n = 0; n < 4; ++n) {
        int col = n0 + wn * 64 + n * 16 + ln15;
#pragma unroll
        for (int r = 0; r < 4; ++r)
          C[(size_t)(row0 + r) * 1024 + col] = f2bf(acc[a][n][r]);
      }
    }
  } else {
    // V transposed: Vt[b][d][n], token gm -> b = gm>>11, n = gm&2047
#pragma unroll
    for (int a = 0; a < 8; ++a) {
      int gm = m0 + wm * 128 + (a >> 2) * 64 + (a & 3) * 16 + kq * 4;
      int b = gm >> 11, nn = gm & 2047;
#pragma unroll
      for (int n = 0; n < 4; ++n) {
        int d = n0 + wn * 64 + n * 16 + ln15;
        ushort4v v;
#pragma unroll
        for (int r = 0; r < 4; ++r) v[r] = f2bf(acc[a][n][r]);
        *(ushort4v*)&Vt[(size_t)b * (2048 * 1024) + (size_t)d * 2048 + nn] = v;
      }
    }
  }
}

// ---------------- launch ----------------
extern "C" void kernel_launch(void* const* d_in, const int* in_sizes, int n_in,
                              void* d_out, int out_size, void* d_ws, size_t ws_size,
                              hipStream_t stream) {
  const float* x = (const float*)d_in[0];
  const float* Wq = (const float*)d_in[1];
  const float* Wk = (const float*)d_in[2];
  const float* Wv = (const float*)d_in[3];
  float* out = (float*)d_out;
  char* ws = (char*)d_ws;

  ushort_t* xb = (ushort_t*)(ws);                   // 16 MB
  ushort_t* wqb = (ushort_t*)(ws + (16ull << 20));  // 2 MB
  ushort_t* wkb = (ushort_t*)(ws + (18ull << 20));  // 2 MB
  ushort_t* wvb = (ushort_t*)(ws + (20ull << 20));  // 2 MB
  ushort_t* Qb = (ushort_t*)(ws + (22ull << 20));   // 16 MB
  ushort_t* Kb = (ushort_t*)(ws + (38ull << 20));   // 16 MB
  ushort_t* Vt = (ushort_t*)(ws + (54ull << 20));   // 16 MB (transposed)
  ushort_t* Eb = (ushort_t*)(ws + (70ull << 20));   // 32 MB exp(S) bf16
  float* rowsum = (float*)(ws + (102ull << 20));    // 32 KB fp32

  cast_all_kernel<<<4096 + 3 * 512 + 4, 256, 0, stream>>>(
      x, Wq, Wk, Wv, xb, wqb, wkb, wvb, rowsum);

  // QKV: 256^2 8-phase core; (32, 4, 3) = 384 blocks @ 1/CU
  dim3 gQKV(8192 / 256, 1024 / 256, 3);
  gemm_qkv8p<<<gQKV, 512, 0, stream>>>(xb, wqb, wkb, wvb, Qb, Kb, Vt);

  // S-GEMM: compact triangular launch, 544 uniform blocks (R3 proven)
  dim3 gS(136, 1, 4);
  gemm_s<<<gS, 256, 0, stream>>>(Qb, Kb, Eb, 0.03125f, rowsum);

  // O-GEMM: complementary-K pairing, longest-K first (R3 proven)
  dim3 gO(2048 / BM, 1024 / BN, 4);  // (16, 8, 4)
  gemm_o<<<gO, 256, 0, stream>>>(Eb, Vt, out, rowsum);
}

// Round 6
// 222.887 us; speedup vs baseline: 1.0724x; 1.0724x over previous
//
#include <hip/hip_runtime.h>
#include <hip/hip_bf16.h>
#include <stdint.h>
#include <math.h>

typedef unsigned short ushort_t;
typedef __attribute__((ext_vector_type(4))) float f32x4;
typedef __attribute__((ext_vector_type(8))) __bf16 bf16x8;
typedef __attribute__((ext_vector_type(8))) unsigned short ushort8;
typedef __attribute__((ext_vector_type(4))) unsigned short ushort4v;

__device__ __forceinline__ float bf2f(ushort_t u) {
  union { unsigned u32; float f; } x; x.u32 = ((unsigned)u) << 16; return x.f;
}
__device__ __forceinline__ ushort_t f2bf(float f) {
  union { float f; unsigned u; } x; x.f = f;
  unsigned r = x.u + 0x7FFF + ((x.u >> 16) & 1);
  return (ushort_t)(r >> 16);
}

// async global->LDS, 16 bytes per lane (global_load_lds_dwordx4)
__device__ __forceinline__ void gld16(const ushort_t* g, ushort_t* l) {
  __builtin_amdgcn_global_load_lds(
      (const __attribute__((address_space(1))) uint32_t*)g,
      (__attribute__((address_space(3))) uint32_t*)l, 16, 0, 0);
}

// ------- merged cast fp32->bf16 (x,Wq,Wk,Wv) + rowsum zero (4 blocks) ------
__global__ __launch_bounds__(256) void cast_all_kernel(
    const float* __restrict__ x, const float* __restrict__ wq,
    const float* __restrict__ wk, const float* __restrict__ wv,
    ushort_t* __restrict__ xb, ushort_t* __restrict__ wqb,
    ushort_t* __restrict__ wkb, ushort_t* __restrict__ wvb,
    float* __restrict__ rowsum) {
  int blk = blockIdx.x;
  if (blk >= 4096 + 1536) {  // rowsum zero: 4 blocks x 256 thr x 8 floats
    int idx = (blk - (4096 + 1536)) * 256 + threadIdx.x;  // 0..1023
    f32x4 z = {0.f, 0.f, 0.f, 0.f};
    ((f32x4*)rowsum)[idx * 2] = z;
    ((f32x4*)rowsum)[idx * 2 + 1] = z;
    return;
  }
  const float* in;
  ushort_t* out;
  int i;
  if (blk < 4096) {               // x: 8388608 elems = 4096 blocks
    in = x; out = xb; i = blk * 256 + threadIdx.x;
  } else {
    int w = (blk - 4096) >> 9;    // 512 blocks per weight matrix
    int lb = (blk - 4096) & 511;
    in = (w == 0) ? wq : (w == 1) ? wk : wv;
    out = (w == 0) ? wqb : (w == 1) ? wkb : wvb;
    i = lb * 256 + threadIdx.x;
  }
  const f32x4* p = (const f32x4*)in;
  f32x4 a = p[2 * i];
  f32x4 b = p[2 * i + 1];
  ushort8 o;
  o[0] = f2bf(a[0]); o[1] = f2bf(a[1]); o[2] = f2bf(a[2]); o[3] = f2bf(a[3]);
  o[4] = f2bf(b[0]); o[5] = f2bf(b[1]); o[6] = f2bf(b[2]); o[7] = f2bf(b[3]);
  *((ushort8*)out + i) = o;
}

// ---------------- PROVEN 128x128 core (256 thr, 3 blocks/CU) --------------
// 903 TF regime: implicit cross-block overlap hides the __syncthreads vmcnt
// drain (m114). XOR k-chunk swizzle on the GLOBAL source offset; readers
// un-swizzle with ln15&7 -> 0 measured bank conflicts. Do NOT touch the
// sync structure (R1/R2/R5 8-phase ports all regressed; R4's occupancy
// squeeze regressed).
#define BM 128
#define BN 128
#define BK 64

__device__ __forceinline__ void gemm_core(
    const ushort_t* __restrict__ A, const ushort_t* __restrict__ B, int Kd,
    int kEnd, int m0, int n0, ushort_t* As, ushort_t* Bs, f32x4 (&acc)[4][4]) {
  int tid = threadIdx.x;
  int lane = tid & 63;
  int wave = tid >> 6;
  int wr = (wave >> 1) * 64;
  int wc = (wave & 1) * 64;
  int ln15 = lane & 15;
  int kq = lane >> 4;

  int row = tid >> 3;                              // 0..31 (base row of chunk)
  int ksw = ((tid & 7) ^ (row & 7)) * 8;           // swizzled k-offset (elems)
  const ushort_t* aB = A + (size_t)(m0 + row) * Kd + ksw;
  const ushort_t* bB = B + (size_t)(n0 + row) * Kd + ksw;
  int xk = ln15 & 7;                               // reader un-swizzle key

  for (int k0 = 0; k0 < kEnd; k0 += BK) {
    __syncthreads();
#pragma unroll
    for (int r = 0; r < 4; ++r) {
      gld16(aB + (size_t)(32 * r) * Kd + k0, &As[(tid + 256 * r) * 8]);
      gld16(bB + (size_t)(32 * r) * Kd + k0, &Bs[(tid + 256 * r) * 8]);
    }
    __syncthreads();
#pragma unroll
    for (int s = 0; s < 2; ++s) {
      bf16x8 af[4], bfr[4];
#pragma unroll
      for (int i = 0; i < 4; ++i)
        af[i] = *(const bf16x8*)
            &As[(wr + i * 16 + ln15) * BK + (((s * 4 + kq) ^ xk) * 8)];
#pragma unroll
      for (int j = 0; j < 4; ++j)
        bfr[j] = *(const bf16x8*)
            &Bs[(wc + j * 16 + ln15) * BK + (((s * 4 + kq) ^ xk) * 8)];
#pragma unroll
      for (int i = 0; i < 4; ++i)
#pragma unroll
        for (int j = 0; j < 4; ++j)
          acc[i][j] = __builtin_amdgcn_mfma_f32_16x16x32_bf16(
              af[i], bfr[j], acc[i][j], 0, 0, 0);
    }
  }
}

// Q/K projection only (z=0 -> Q, z=1 -> K). V is computed in gemm_sv,
// overlapped with the S-GEMM (V is not needed until the O-GEMM).
__global__ __launch_bounds__(256, 3) void gemm_qk(
    const ushort_t* __restrict__ xb, const ushort_t* __restrict__ wq,
    const ushort_t* __restrict__ wk, ushort_t* __restrict__ Qb,
    ushort_t* __restrict__ Kb) {
  int m0 = blockIdx.x * BM, n0 = blockIdx.y * BN;
  int z = blockIdx.z;
  const ushort_t* B = (z == 0) ? wq : wk;

  __shared__ ushort_t As[BM * BK];
  __shared__ ushort_t Bs[BN * BK];

  f32x4 acc[4][4];
#pragma unroll
  for (int i = 0; i < 4; ++i)
#pragma unroll
    for (int j = 0; j < 4; ++j) acc[i][j] = f32x4{0.f, 0.f, 0.f, 0.f};

  gemm_core(xb, B, 1024, 1024, m0, n0, As, Bs, acc);

  int tid = threadIdx.x;
  int lane = tid & 63;
  int wave = tid >> 6;
  int wr = (wave >> 1) * 64;
  int wc = (wave & 1) * 64;
  int ln15 = lane & 15;
  int kq = lane >> 4;

  // C/D layout (verified m89): col = lane&15, row = (lane>>4)*4 + reg
  ushort_t* C = (z == 0) ? Qb : Kb;
#pragma unroll
  for (int i = 0; i < 4; ++i) {
    int row0 = m0 + wr + i * 16 + kq * 4;
#pragma unroll
    for (int j = 0; j < 4; ++j) {
      int col = n0 + wc + j * 16 + ln15;
#pragma unroll
      for (int r = 0; r < 4; ++r)
        C[(size_t)(row0 + r) * 1024 + col] = f2bf(acc[i][j][r]);
    }
  }
}

// Combined S-GEMM + V-projection launch. blockIdx.x < 136: S tile
// (triangular causal decode, per-batch z); blockIdx.x >= 136: V block
// (vid = (x-136) + 128*z, m = vid>>3 of 64, n = vid&7). Per-block work is
// identical (34.4 MF, K=1024) so the dispatcher load-balances uniformly;
// V rides in S's spare CU capacity instead of serializing in the QKV stage.
__global__ __launch_bounds__(256, 3) void gemm_sv(
    const ushort_t* __restrict__ Qg, const ushort_t* __restrict__ Kg,
    const ushort_t* __restrict__ xb, const ushort_t* __restrict__ wv,
    ushort_t* __restrict__ Eg, ushort_t* __restrict__ Vt,
    float scale, float* __restrict__ rowsum) {
  int bx = blockIdx.x;
  int bz = blockIdx.z;
  bool isS = bx < 136;
  int m0, n0;
  const ushort_t *A, *B;
  if (isS) {
    int t = bx;  // 0..135 triangular index
    int m = (int)((sqrtf(8.f * (float)t + 1.f) - 1.f) * 0.5f);
    while ((m + 1) * (m + 2) / 2 <= t) ++m;
    while (m * (m + 1) / 2 > t) --m;
    int n = t - m * (m + 1) / 2;            // 0..m
    m0 = m * BM; n0 = n * BN;
    A = Qg + (size_t)bz * (2048 * 1024);
    B = Kg + (size_t)bz * (2048 * 1024);
  } else {
    int vid = (bx - 136) + 128 * bz;        // 0..511
    m0 = (vid >> 3) * BM;                   // global token-row tile (8192)
    n0 = (vid & 7) * BN;
    A = xb;
    B = wv;
  }

  __shared__ ushort_t As[BM * BK];
  __shared__ ushort_t Bs[BN * BK];

  f32x4 acc[4][4];
#pragma unroll
  for (int i = 0; i < 4; ++i)
#pragma unroll
    for (int j = 0; j < 4; ++j) acc[i][j] = f32x4{0.f, 0.f, 0.f, 0.f};

  gemm_core(A, B, 1024, 1024, m0, n0, As, Bs, acc);

  int tid = threadIdx.x;
  int lane = tid & 63;
  int wave = tid >> 6;
  int wr = (wave >> 1) * 64;
  int wc = (wave & 1) * 64;
  int ln15 = lane & 15;
  int kq = lane >> 4;

  if (isS) {
    // S epilogue: exp (no max-sub; |s*scale| < ~2.5) + bf16 E + rowsum
    ushort_t* C = Eg + (size_t)bz * (2048 * 2048);
    float* rs = rowsum + (size_t)bz * 2048;
#pragma unroll
    for (int i = 0; i < 4; ++i) {
      int row0 = m0 + wr + i * 16 + kq * 4;
#pragma unroll
      for (int r = 0; r < 4; ++r) {
        int grow = row0 + r;
        float psum = 0.f;
#pragma unroll
        for (int j = 0; j < 4; ++j) {
          int col = n0 + wc + j * 16 + ln15;
          float e = (col <= grow) ? __expf(acc[i][j][r] * scale) : 0.f;
          C[(size_t)grow * 2048 + col] = f2bf(e);
          psum += e;
        }
        psum += __shfl_xor(psum, 1);
        psum += __shfl_xor(psum, 2);
        psum += __shfl_xor(psum, 4);
        psum += __shfl_xor(psum, 8);
        if (ln15 == 0) atomicAdd(&rs[grow], psum);
      }
    }
  } else {
    // V transposed epilogue: Vt[b][d][n], token gm -> b = gm>>11, n = gm&2047
#pragma unroll
    for (int i = 0; i < 4; ++i) {
      int gm = m0 + wr + i * 16 + kq * 4;
      int b = gm >> 11, nn = gm & 2047;
#pragma unroll
      for (int j = 0; j < 4; ++j) {
        int d = n0 + wc + j * 16 + ln15;
        ushort4v v;
#pragma unroll
        for (int r = 0; r < 4; ++r) v[r] = f2bf(acc[i][j][r]);
        *(ushort4v*)&Vt[(size_t)b * (2048 * 1024) + (size_t)d * 2048 + nn] = v;
      }
    }
  }
}

// O-GEMM: complementary-K pairing + longest-K first (z<2 -> m reversed).
__global__ __launch_bounds__(256, 3) void gemm_o(
    const ushort_t* __restrict__ Eg, const ushort_t* __restrict__ Vg,
    float* __restrict__ Og, const float* __restrict__ rowsum) {
  int m = (blockIdx.z < 2) ? (int)(gridDim.x - 1 - blockIdx.x)
                           : (int)blockIdx.x;
  int m0 = m * BM, n0 = blockIdx.y * BN;
  int kEnd = min(2048, m0 + BM);
  int bz = blockIdx.z;
  const ushort_t* A = Eg + (size_t)bz * (2048 * 2048);
  const ushort_t* B = Vg + (size_t)bz * (1024 * 2048);

  __shared__ ushort_t As[BM * BK];
  __shared__ ushort_t Bs[BN * BK];

  f32x4 acc[4][4];
#pragma unroll
  for (int i = 0; i < 4; ++i)
#pragma unroll
    for (int j = 0; j < 4; ++j) acc[i][j] = f32x4{0.f, 0.f, 0.f, 0.f};

  gemm_core(A, B, 2048, kEnd, m0, n0, As, Bs, acc);

  int tid = threadIdx.x;
  int lane = tid & 63;
  int wave = tid >> 6;
  int wr = (wave >> 1) * 64;
  int wc = (wave & 1) * 64;
  int ln15 = lane & 15;
  int kq = lane >> 4;

  float* C = Og + (size_t)bz * (2048 * 1024);
  const float* rs = rowsum + (size_t)bz * 2048;
#pragma unroll
  for (int i = 0; i < 4; ++i) {
    int row0 = m0 + wr + i * 16 + kq * 4;
#pragma unroll
    for (int r = 0; r < 4; ++r) {
      float inv = 1.0f / rs[row0 + r];
#pragma unroll
      for (int j = 0; j < 4; ++j) {
        int col = n0 + wc + j * 16 + ln15;
        C[(size_t)(row0 + r) * 1024 + col] = acc[i][j][r] * inv;
      }
    }
  }
}

// ---------------- launch ----------------
extern "C" void kernel_launch(void* const* d_in, const int* in_sizes, int n_in,
                              void* d_out, int out_size, void* d_ws, size_t ws_size,
                              hipStream_t stream) {
  const float* x = (const float*)d_in[0];
  const float* Wq = (const float*)d_in[1];
  const float* Wk = (const float*)d_in[2];
  const float* Wv = (const float*)d_in[3];
  float* out = (float*)d_out;
  char* ws = (char*)d_ws;

  ushort_t* xb = (ushort_t*)(ws);                   // 16 MB
  ushort_t* wqb = (ushort_t*)(ws + (16ull << 20));  // 2 MB
  ushort_t* wkb = (ushort_t*)(ws + (18ull << 20));  // 2 MB
  ushort_t* wvb = (ushort_t*)(ws + (20ull << 20));  // 2 MB
  ushort_t* Qb = (ushort_t*)(ws + (22ull << 20));   // 16 MB
  ushort_t* Kb = (ushort_t*)(ws + (38ull << 20));   // 16 MB
  ushort_t* Vt = (ushort_t*)(ws + (54ull << 20));   // 16 MB (transposed)
  ushort_t* Eb = (ushort_t*)(ws + (70ull << 20));   // 32 MB exp(S) bf16
  float* rowsum = (float*)(ws + (102ull << 20));    // 32 KB fp32

  cast_all_kernel<<<4096 + 3 * 512 + 4, 256, 0, stream>>>(
      x, Wq, Wk, Wv, xb, wqb, wkb, wvb, rowsum);

  // Q,K projections only (V moved into gemm_sv)
  dim3 gQK(8192 / BM, 1024 / BN, 2);  // (64, 8, 2)
  gemm_qk<<<gQK, 256, 0, stream>>>(xb, wqb, wkb, Qb, Kb);

  // S-GEMM (544 triangular blocks) + V-projection (512 blocks), one launch
  dim3 gSV(136 + 128, 1, 4);
  gemm_sv<<<gSV, 256, 0, stream>>>(Qb, Kb, xb, wvb, Eb, Vt, 0.03125f, rowsum);

  // O-GEMM: complementary-K pairing, longest-K first
  dim3 gO(2048 / BM, 1024 / BN, 4);  // (16, 8, 4)
  gemm_o<<<gO, 256, 0, stream>>>(Eb, Vt, out, rowsum);
}

// Round 7
// 208.962 us; speedup vs baseline: 1.1438x; 1.0666x over previous
//
#include <hip/hip_runtime.h>
#include <hip/hip_bf16.h>
#include <stdint.h>
#include <math.h>

typedef unsigned short ushort_t;
typedef __attribute__((ext_vector_type(4))) float f32x4;
typedef __attribute__((ext_vector_type(8))) __bf16 bf16x8;
typedef __attribute__((ext_vector_type(8))) unsigned short ushort8;
typedef __attribute__((ext_vector_type(4))) unsigned short ushort4v;

__device__ __forceinline__ float bf2f(ushort_t u) {
  union { unsigned u32; float f; } x; x.u32 = ((unsigned)u) << 16; return x.f;
}
__device__ __forceinline__ ushort_t f2bf(float f) {
  union { float f; unsigned u; } x; x.f = f;
  unsigned r = x.u + 0x7FFF + ((x.u >> 16) & 1);
  return (ushort_t)(r >> 16);
}

// async global->LDS, 16 bytes per lane (global_load_lds_dwordx4)
__device__ __forceinline__ void gld16(const ushort_t* g, ushort_t* l) {
  __builtin_amdgcn_global_load_lds(
      (const __attribute__((address_space(1))) uint32_t*)g,
      (__attribute__((address_space(3))) uint32_t*)l, 16, 0, 0);
}

// ------- merged cast fp32->bf16 (x,Wq,Wk,Wv) + rowsum zero (4 blocks) ------
__global__ __launch_bounds__(256) void cast_all_kernel(
    const float* __restrict__ x, const float* __restrict__ wq,
    const float* __restrict__ wk, const float* __restrict__ wv,
    ushort_t* __restrict__ xb, ushort_t* __restrict__ wqb,
    ushort_t* __restrict__ wkb, ushort_t* __restrict__ wvb,
    float* __restrict__ rowsum) {
  int blk = blockIdx.x;
  if (blk >= 4096 + 1536) {  // rowsum zero: 4 blocks x 256 thr x 8 floats
    int idx = (blk - (4096 + 1536)) * 256 + threadIdx.x;  // 0..1023
    f32x4 z = {0.f, 0.f, 0.f, 0.f};
    ((f32x4*)rowsum)[idx * 2] = z;
    ((f32x4*)rowsum)[idx * 2 + 1] = z;
    return;
  }
  const float* in;
  ushort_t* out;
  int i;
  if (blk < 4096) {               // x: 8388608 elems = 4096 blocks
    in = x; out = xb; i = blk * 256 + threadIdx.x;
  } else {
    int w = (blk - 4096) >> 9;    // 512 blocks per weight matrix
    int lb = (blk - 4096) & 511;
    in = (w == 0) ? wq : (w == 1) ? wk : wv;
    out = (w == 0) ? wqb : (w == 1) ? wkb : wvb;
    i = lb * 256 + threadIdx.x;
  }
  const f32x4* p = (const f32x4*)in;
  f32x4 a = p[2 * i];
  f32x4 b = p[2 * i + 1];
  ushort8 o;
  o[0] = f2bf(a[0]); o[1] = f2bf(a[1]); o[2] = f2bf(a[2]); o[3] = f2bf(a[3]);
  o[4] = f2bf(b[0]); o[5] = f2bf(b[1]); o[6] = f2bf(b[2]); o[7] = f2bf(b[3]);
  *((ushort8*)out + i) = o;
}

// ---------------- PROVEN 128x128 core (256 thr, 3 blocks/CU) --------------
// 903 TF regime: implicit cross-block overlap hides the __syncthreads vmcnt
// drain (m114). XOR k-chunk swizzle on the GLOBAL source offset; readers
// un-swizzle with ln15&7 -> 0 measured bank conflicts. Do NOT touch the
// sync structure (R1/R2/R5 8-phase ports regressed; R4 occupancy squeeze
// regressed).
#define BM 128
#define BN 128
#define BK 64

__device__ __forceinline__ void gemm_core(
    const ushort_t* __restrict__ A, const ushort_t* __restrict__ B, int Kd,
    int kEnd, int m0, int n0, ushort_t* As, ushort_t* Bs, f32x4 (&acc)[4][4]) {
  int tid = threadIdx.x;
  int lane = tid & 63;
  int wave = tid >> 6;
  int wr = (wave >> 1) * 64;
  int wc = (wave & 1) * 64;
  int ln15 = lane & 15;
  int kq = lane >> 4;

  int row = tid >> 3;                              // 0..31 (base row of chunk)
  int ksw = ((tid & 7) ^ (row & 7)) * 8;           // swizzled k-offset (elems)
  const ushort_t* aB = A + (size_t)(m0 + row) * Kd + ksw;
  const ushort_t* bB = B + (size_t)(n0 + row) * Kd + ksw;
  int xk = ln15 & 7;                               // reader un-swizzle key

  for (int k0 = 0; k0 < kEnd; k0 += BK) {
    __syncthreads();
#pragma unroll
    for (int r = 0; r < 4; ++r) {
      gld16(aB + (size_t)(32 * r) * Kd + k0, &As[(tid + 256 * r) * 8]);
      gld16(bB + (size_t)(32 * r) * Kd + k0, &Bs[(tid + 256 * r) * 8]);
    }
    __syncthreads();
#pragma unroll
    for (int s = 0; s < 2; ++s) {
      bf16x8 af[4], bfr[4];
#pragma unroll
      for (int i = 0; i < 4; ++i)
        af[i] = *(const bf16x8*)
            &As[(wr + i * 16 + ln15) * BK + (((s * 4 + kq) ^ xk) * 8)];
#pragma unroll
      for (int j = 0; j < 4; ++j)
        bfr[j] = *(const bf16x8*)
            &Bs[(wc + j * 16 + ln15) * BK + (((s * 4 + kq) ^ xk) * 8)];
#pragma unroll
      for (int i = 0; i < 4; ++i)
#pragma unroll
        for (int j = 0; j < 4; ++j)
          acc[i][j] = __builtin_amdgcn_mfma_f32_16x16x32_bf16(
              af[i], bfr[j], acc[i][j], 0, 0, 0);
    }
  }
}

// Q/K projection only (z=0 -> Q, z=1 -> K). V is computed in gemm_sv.
// XCD locality here is already good: linear = x + 64y + 512z, 64%8==0 ->
// all n-tiles sharing an x-panel land on the same XCD.
__global__ __launch_bounds__(256, 3) void gemm_qk(
    const ushort_t* __restrict__ xb, const ushort_t* __restrict__ wq,
    const ushort_t* __restrict__ wk, ushort_t* __restrict__ Qb,
    ushort_t* __restrict__ Kb) {
  int m0 = blockIdx.x * BM, n0 = blockIdx.y * BN;
  int z = blockIdx.z;
  const ushort_t* B = (z == 0) ? wq : wk;

  __shared__ ushort_t As[BM * BK];
  __shared__ ushort_t Bs[BN * BK];

  f32x4 acc[4][4];
#pragma unroll
  for (int i = 0; i < 4; ++i)
#pragma unroll
    for (int j = 0; j < 4; ++j) acc[i][j] = f32x4{0.f, 0.f, 0.f, 0.f};

  gemm_core(xb, B, 1024, 1024, m0, n0, As, Bs, acc);

  int tid = threadIdx.x;
  int lane = tid & 63;
  int wave = tid >> 6;
  int wr = (wave >> 1) * 64;
  int wc = (wave & 1) * 64;
  int ln15 = lane & 15;
  int kq = lane >> 4;

  // C/D layout (verified m89): col = lane&15, row = (lane>>4)*4 + reg
  ushort_t* C = (z == 0) ? Qb : Kb;
#pragma unroll
  for (int i = 0; i < 4; ++i) {
    int row0 = m0 + wr + i * 16 + kq * 4;
#pragma unroll
    for (int j = 0; j < 4; ++j) {
      int col = n0 + wc + j * 16 + ln15;
#pragma unroll
      for (int r = 0; r < 4; ++r)
        C[(size_t)(row0 + r) * 1024 + col] = f2bf(acc[i][j][r]);
    }
  }
}

// Combined S-GEMM + V-projection, XCD-PINNED. R6 measured FETCH=171MB
// (ideal ~50MB), 3.3TB/s, MfmaUtil 21% -> cache-miss-bound because grid
// (264,1,4) spreads every batch across all 8 XCDs (264%8==0) and the four
// 4MB K-panels thrash each 4MB L2. Remap: flat grid 1056 = 8 XCDs x 132
// slots; XCD = linear%8 (HW round-robin), batch z = xcd>>1 (2 XCDs/batch),
// idx = (xcd&1)*132 + slot in [0,264) = 136 S-tiles + 128 V-blocks (exact).
// Per-XCD working set drops ~32MB -> ~6-8MB. If the %8 mapping assumption
// is wrong this degrades to the old uniform spread (bijection holds).
__global__ __launch_bounds__(256, 3) void gemm_sv(
    const ushort_t* __restrict__ Qg, const ushort_t* __restrict__ Kg,
    const ushort_t* __restrict__ xb, const ushort_t* __restrict__ wv,
    ushort_t* __restrict__ Eg, ushort_t* __restrict__ Vt,
    float scale, float* __restrict__ rowsum) {
  int L = blockIdx.x;
  int xcd = L & 7;
  int slot = L >> 3;                        // 0..131
  int bz = xcd >> 1;                        // 0..3 (2 XCDs per batch)
  int idx = ((xcd & 1) * 132) + slot;       // 0..263
  bool isS = idx < 136;
  int m0, n0;
  const ushort_t *A, *B;
  if (isS) {
    int t = idx;  // 0..135 triangular index
    int m = (int)((sqrtf(8.f * (float)t + 1.f) - 1.f) * 0.5f);
    while ((m + 1) * (m + 2) / 2 <= t) ++m;
    while (m * (m + 1) / 2 > t) --m;
    int n = t - m * (m + 1) / 2;            // 0..m
    m0 = m * BM; n0 = n * BN;
    A = Qg + (size_t)bz * (2048 * 1024);
    B = Kg + (size_t)bz * (2048 * 1024);
  } else {
    int vid = (idx - 136) + 128 * bz;       // 0..511
    m0 = (vid >> 3) * BM;                   // global token-row tile (8192)
    n0 = (vid & 7) * BN;
    A = xb;
    B = wv;
  }

  __shared__ ushort_t As[BM * BK];
  __shared__ ushort_t Bs[BN * BK];

  f32x4 acc[4][4];
#pragma unroll
  for (int i = 0; i < 4; ++i)
#pragma unroll
    for (int j = 0; j < 4; ++j) acc[i][j] = f32x4{0.f, 0.f, 0.f, 0.f};

  gemm_core(A, B, 1024, 1024, m0, n0, As, Bs, acc);

  int tid = threadIdx.x;
  int lane = tid & 63;
  int wave = tid >> 6;
  int wr = (wave >> 1) * 64;
  int wc = (wave & 1) * 64;
  int ln15 = lane & 15;
  int kq = lane >> 4;

  if (isS) {
    // S epilogue: exp (no max-sub; |s*scale| < ~2.5) + bf16 E + rowsum
    ushort_t* C = Eg + (size_t)bz * (2048 * 2048);
    float* rs = rowsum + (size_t)bz * 2048;
#pragma unroll
    for (int i = 0; i < 4; ++i) {
      int row0 = m0 + wr + i * 16 + kq * 4;
#pragma unroll
      for (int r = 0; r < 4; ++r) {
        int grow = row0 + r;
        float psum = 0.f;
#pragma unroll
        for (int j = 0; j < 4; ++j) {
          int col = n0 + wc + j * 16 + ln15;
          float e = (col <= grow) ? __expf(acc[i][j][r] * scale) : 0.f;
          C[(size_t)grow * 2048 + col] = f2bf(e);
          psum += e;
        }
        psum += __shfl_xor(psum, 1);
        psum += __shfl_xor(psum, 2);
        psum += __shfl_xor(psum, 4);
        psum += __shfl_xor(psum, 8);
        if (ln15 == 0) atomicAdd(&rs[grow], psum);
      }
    }
  } else {
    // V transposed epilogue: Vt[b][d][n], token gm -> b = gm>>11, n = gm&2047
#pragma unroll
    for (int i = 0; i < 4; ++i) {
      int gm = m0 + wr + i * 16 + kq * 4;
      int b = gm >> 11, nn = gm & 2047;
#pragma unroll
      for (int j = 0; j < 4; ++j) {
        int d = n0 + wc + j * 16 + ln15;
        ushort4v v;
#pragma unroll
        for (int r = 0; r < 4; ++r) v[r] = f2bf(acc[i][j][r]);
        *(ushort4v*)&Vt[(size_t)b * (2048 * 1024) + (size_t)d * 2048 + nn] = v;
      }
    }
  }
}

// O-GEMM, XCD-PINNED: flat grid 512 = 8 XCDs x 64 slots, batch = xcd>>1.
// Within an XCD: n = idx&7, mm = idx>>3; m = mm&1 ? 15-(mm>>1) : mm>>1
// interleaves long/short causal K so each XCD half gets equal total K
// (68*128) -> balance preserved + per-XCD working set ~ one batch's Vt.
__global__ __launch_bounds__(256, 3) void gemm_o(
    const ushort_t* __restrict__ Eg, const ushort_t* __restrict__ Vg,
    float* __restrict__ Og, const float* __restrict__ rowsum) {
  int L = blockIdx.x;
  int xcd = L & 7;
  int slot = L >> 3;                        // 0..63
  int bz = xcd >> 1;
  int idx = ((xcd & 1) * 64) + slot;        // 0..127
  int n = idx & 7;
  int mm = idx >> 3;                        // 0..15
  int m = (mm & 1) ? (15 - (mm >> 1)) : (mm >> 1);
  int m0 = m * BM, n0 = n * BN;
  int kEnd = min(2048, m0 + BM);
  const ushort_t* A = Eg + (size_t)bz * (2048 * 2048);
  const ushort_t* B = Vg + (size_t)bz * (1024 * 2048);

  __shared__ ushort_t As[BM * BK];
  __shared__ ushort_t Bs[BN * BK];

  f32x4 acc[4][4];
#pragma unroll
  for (int i = 0; i < 4; ++i)
#pragma unroll
    for (int j = 0; j < 4; ++j) acc[i][j] = f32x4{0.f, 0.f, 0.f, 0.f};

  gemm_core(A, B, 2048, kEnd, m0, n0, As, Bs, acc);

  int tid = threadIdx.x;
  int lane = tid & 63;
  int wave = tid >> 6;
  int wr = (wave >> 1) * 64;
  int wc = (wave & 1) * 64;
  int ln15 = lane & 15;
  int kq = lane >> 4;

  float* C = Og + (size_t)bz * (2048 * 1024);
  const float* rs = rowsum + (size_t)bz * 2048;
#pragma unroll
  for (int i = 0; i < 4; ++i) {
    int row0 = m0 + wr + i * 16 + kq * 4;
#pragma unroll
    for (int r = 0; r < 4; ++r) {
      float inv = 1.0f / rs[row0 + r];
#pragma unroll
      for (int j = 0; j < 4; ++j) {
        int col = n0 + wc + j * 16 + ln15;
        C[(size_t)(row0 + r) * 1024 + col] = acc[i][j][r] * inv;
      }
    }
  }
}

// ---------------- launch ----------------
extern "C" void kernel_launch(void* const* d_in, const int* in_sizes, int n_in,
                              void* d_out, int out_size, void* d_ws, size_t ws_size,
                              hipStream_t stream) {
  const float* x = (const float*)d_in[0];
  const float* Wq = (const float*)d_in[1];
  const float* Wk = (const float*)d_in[2];
  const float* Wv = (const float*)d_in[3];
  float* out = (float*)d_out;
  char* ws = (char*)d_ws;

  ushort_t* xb = (ushort_t*)(ws);                   // 16 MB
  ushort_t* wqb = (ushort_t*)(ws + (16ull << 20));  // 2 MB
  ushort_t* wkb = (ushort_t*)(ws + (18ull << 20));  // 2 MB
  ushort_t* wvb = (ushort_t*)(ws + (20ull << 20));  // 2 MB
  ushort_t* Qb = (ushort_t*)(ws + (22ull << 20));   // 16 MB
  ushort_t* Kb = (ushort_t*)(ws + (38ull << 20));   // 16 MB
  ushort_t* Vt = (ushort_t*)(ws + (54ull << 20));   // 16 MB (transposed)
  ushort_t* Eb = (ushort_t*)(ws + (70ull << 20));   // 32 MB exp(S) bf16
  float* rowsum = (float*)(ws + (102ull << 20));    // 32 KB fp32

  cast_all_kernel<<<4096 + 3 * 512 + 4, 256, 0, stream>>>(
      x, Wq, Wk, Wv, xb, wqb, wkb, wvb, rowsum);

  // Q,K projections only (V moved into gemm_sv)
  dim3 gQK(8192 / BM, 1024 / BN, 2);  // (64, 8, 2)
  gemm_qk<<<gQK, 256, 0, stream>>>(xb, wqb, wkb, Qb, Kb);

  // S-GEMM + V-projection, XCD-pinned flat grid (1056 = 8 x 132)
  gemm_sv<<<dim3(1056, 1, 1), 256, 0, stream>>>(
      Qb, Kb, xb, wvb, Eb, Vt, 0.03125f, rowsum);

  // O-GEMM, XCD-pinned flat grid (512 = 8 x 64), K-balanced interleave
  gemm_o<<<dim3(512, 1, 1), 256, 0, stream>>>(Eb, Vt, out, rowsum);
}